// Round 4
// baseline (1715.196 us; speedup 1.0000x reference)
//
#include <hip/hip_runtime.h>
#include <hip/hip_bf16.h>

#define B_ 2
#define S_ 2048
#define HID_ 4096
#define NH_ 32
#define NKV_ 8
#define HD_ 128
#define T_ (B_*S_)

typedef __bf16 bf16;
typedef __bf16 bf16x8 __attribute__((ext_vector_type(8)));
typedef __bf16 bf16x4 __attribute__((ext_vector_type(4)));
typedef float f32x4 __attribute__((ext_vector_type(4)));

// async global->LDS, 16B per lane; LDS dest = base + lane*16 (wave-uniform base)
__device__ __forceinline__ void load_lds16(const void* g, void* l) {
  __builtin_amdgcn_global_load_lds((const __attribute__((address_space(1))) void*)g,
                                   (__attribute__((address_space(3))) void*)l, 16, 0, 0);
}

// DPP row_ror cross-lane (16-lane ring) — VALU-speed reduction, no LDS pipe
#define DPP_ROR(x, n) __int_as_float(__builtin_amdgcn_update_dpp( \
    __float_as_int(x), __float_as_int(x), 0x120 | (n), 0xf, 0xf, false))
__device__ __forceinline__ float red16_max(float x) {
  x = fmaxf(x, DPP_ROR(x, 1)); x = fmaxf(x, DPP_ROR(x, 2));
  x = fmaxf(x, DPP_ROR(x, 4)); x = fmaxf(x, DPP_ROR(x, 8));
  return x;
}
__device__ __forceinline__ float red16_sum(float x) {
  x += DPP_ROR(x, 1); x += DPP_ROR(x, 2);
  x += DPP_ROR(x, 4); x += DPP_ROR(x, 8);
  return x;
}

// ---------------- convert fp32 -> bf16 ----------------
__global__ __launch_bounds__(256) void cvt_bf16_kernel(const float* __restrict__ in,
                                                       bf16* __restrict__ out, int n4) {
  int idx = blockIdx.x * 256 + threadIdx.x;
  if (idx >= n4) return;
  float4 v = ((const float4*)in)[idx];
  bf16x4 o;
  o.x = (bf16)v.x; o.y = (bf16)v.y; o.z = (bf16)v.z; o.w = (bf16)v.w;
  ((bf16x4*)out)[idx] = o;
}

// ---------------- dequant int4(stored int32) -> bf16 ----------------
__global__ __launch_bounds__(256) void dequant_kernel(const int* __restrict__ qw,
                                                      const float* __restrict__ scale,
                                                      bf16* __restrict__ out,
                                                      int OD, int ID) {
  int idx = blockIdx.x * 256 + threadIdx.x;
  int perRow = ID >> 3;
  int total = OD * perRow;
  if (idx >= total) return;
  int o = idx / perRow;
  int ic = idx - o * perRow;
  float s = scale[o * (ID >> 7) + ((ic * 8) >> 7)];
  const int* q = qw + (size_t)o * ID + ic * 8;
  int4 q0 = *(const int4*)q;
  int4 q1 = *(const int4*)(q + 4);
  bf16x8 r;
  r[0] = (bf16)((q0.x - 8) * s);
  r[1] = (bf16)((q0.y - 8) * s);
  r[2] = (bf16)((q0.z - 8) * s);
  r[3] = (bf16)((q0.w - 8) * s);
  r[4] = (bf16)((q1.x - 8) * s);
  r[5] = (bf16)((q1.y - 8) * s);
  r[6] = (bf16)((q1.z - 8) * s);
  r[7] = (bf16)((q1.w - 8) * s);
  *(bf16x8*)(out + (size_t)o * ID + ic * 8) = r;
}

// ---------------- GEMM: C[M][N] = A[M][K] * B[N][K]^T (128-tile, kept for N=1024 shapes) ----
__global__ __launch_bounds__(256) void gemm_bt_kernel(const bf16* __restrict__ A,
                                                      const bf16* __restrict__ Bm,
                                                      void* __restrict__ Cout,
                                                      int N, int K, int c_fp32) {
  __shared__ bf16 As[8192];
  __shared__ bf16 Bs[8192];
  int tid = threadIdx.x;
  int wave = tid >> 6, lane = tid & 63, quad = lane >> 4, l16 = lane & 15;
  int m0 = blockIdx.y * 128, n0 = blockIdx.x * 128;
  int wm = (wave >> 1) * 64, wn = (wave & 1) * 64;

  int srow = lane >> 3;
  int schunk = (lane & 7) ^ (srow & 7);
  const bf16* Ab[4];
  const bf16* Bb[4];
#pragma unroll
  for (int u = 0; u < 4; u++) {
    int t = wave + 4 * u;
    Ab[u] = A  + (size_t)(m0 + 8 * t + srow) * K + schunk * 8;
    Bb[u] = Bm + (size_t)(n0 + 8 * t + srow) * K + schunk * 8;
  }

  f32x4 acc[4][4];
#pragma unroll
  for (int mt = 0; mt < 4; mt++)
#pragma unroll
    for (int nt = 0; nt < 4; nt++) acc[mt][nt] = (f32x4){0.f, 0.f, 0.f, 0.f};

  for (int k0 = 0; k0 < K; k0 += 64) {
    __syncthreads();
#pragma unroll
    for (int u = 0; u < 4; u++) {
      int t = wave + 4 * u;
      load_lds16(Ab[u] + k0, (char*)As + t * 1024);
      load_lds16(Bb[u] + k0, (char*)Bs + t * 1024);
    }
    __syncthreads();
#pragma unroll
    for (int kk = 0; kk < 2; kk++) {
      bf16x8 af[4], bfr[4];
#pragma unroll
      for (int mt = 0; mt < 4; mt++) {
        int r = wm + mt * 16 + l16;
        af[mt] = *(const bf16x8*)((const char*)As + r * 128 + (((kk * 4 + quad) ^ (r & 7)) << 4));
      }
#pragma unroll
      for (int nt = 0; nt < 4; nt++) {
        int r = wn + nt * 16 + l16;
        bfr[nt] = *(const bf16x8*)((const char*)Bs + r * 128 + (((kk * 4 + quad) ^ (r & 7)) << 4));
      }
#pragma unroll
      for (int mt = 0; mt < 4; mt++)
#pragma unroll
        for (int nt = 0; nt < 4; nt++)
          acc[mt][nt] = __builtin_amdgcn_mfma_f32_16x16x32_bf16(af[mt], bfr[nt], acc[mt][nt], 0, 0, 0);
    }
  }

#pragma unroll
  for (int mt = 0; mt < 4; mt++)
#pragma unroll
    for (int nt = 0; nt < 4; nt++)
#pragma unroll
      for (int r = 0; r < 4; r++) {
        int rr = m0 + wm + mt * 16 + quad * 4 + r;
        int cc = n0 + wn + nt * 16 + l16;
        if (c_fp32) ((float*)Cout)[(size_t)rr * N + cc] = acc[mt][nt][r];
        else        ((bf16*)Cout)[(size_t)rr * N + cc] = (bf16)acc[mt][nt][r];
      }
}

// ---------------- 128-tile GEMM + fused RoPE epilogue (kept for K projection, N=1024) ----
__global__ __launch_bounds__(256) void gemm_rope_kernel(const bf16* __restrict__ A,
                                                        const bf16* __restrict__ Bm,
                                                        bf16* __restrict__ Out,
                                                        int N, int K,
                                                        const float* __restrict__ cosT,
                                                        const float* __restrict__ sinT,
                                                        float outscale) {
  __shared__ char smem[32768];
  bf16* As = (bf16*)smem;
  bf16* Bs = (bf16*)(smem + 16384);
  float* Ex = (float*)smem;   // 256*17 floats, aliases As/Bs after main loop
  int tid = threadIdx.x;
  int wave = tid >> 6, lane = tid & 63, quad = lane >> 4, l16 = lane & 15;
  int m0 = blockIdx.y * 128, n0 = blockIdx.x * 128;
  int wm = (wave >> 1) * 64, wn = (wave & 1) * 64;

  int srow = lane >> 3;
  int schunk = (lane & 7) ^ (srow & 7);
  const bf16* Ab[4];
  const bf16* Bb[4];
#pragma unroll
  for (int u = 0; u < 4; u++) {
    int t = wave + 4 * u;
    Ab[u] = A  + (size_t)(m0 + 8 * t + srow) * K + schunk * 8;
    Bb[u] = Bm + (size_t)(n0 + 8 * t + srow) * K + schunk * 8;
  }

  f32x4 acc[4][4];
#pragma unroll
  for (int mt = 0; mt < 4; mt++)
#pragma unroll
    for (int nt = 0; nt < 4; nt++) acc[mt][nt] = (f32x4){0.f, 0.f, 0.f, 0.f};

  for (int k0 = 0; k0 < K; k0 += 64) {
    __syncthreads();
#pragma unroll
    for (int u = 0; u < 4; u++) {
      int t = wave + 4 * u;
      load_lds16(Ab[u] + k0, (char*)As + t * 1024);
      load_lds16(Bb[u] + k0, (char*)Bs + t * 1024);
    }
    __syncthreads();
#pragma unroll
    for (int kk = 0; kk < 2; kk++) {
      bf16x8 af[4], bfr[4];
#pragma unroll
      for (int mt = 0; mt < 4; mt++) {
        int r = wm + mt * 16 + l16;
        af[mt] = *(const bf16x8*)((const char*)As + r * 128 + (((kk * 4 + quad) ^ (r & 7)) << 4));
      }
#pragma unroll
      for (int nt = 0; nt < 4; nt++) {
        int r = wn + nt * 16 + l16;
        bfr[nt] = *(const bf16x8*)((const char*)Bs + r * 128 + (((kk * 4 + quad) ^ (r & 7)) << 4));
      }
#pragma unroll
      for (int mt = 0; mt < 4; mt++)
#pragma unroll
        for (int nt = 0; nt < 4; nt++)
          acc[mt][nt] = __builtin_amdgcn_mfma_f32_16x16x32_bf16(af[mt], bfr[nt], acc[mt][nt], 0, 0, 0);
    }
  }

  int myb = tid * 17;
  int pb = (tid ^ 64) * 17;    // partner: other 64-col half, same lane/regs
#pragma unroll
  for (int mt = 0; mt < 4; mt++) {
    __syncthreads();
#pragma unroll
    for (int nt = 0; nt < 4; nt++)
#pragma unroll
      for (int r = 0; r < 4; r++)
        Ex[myb + nt * 4 + r] = acc[mt][nt][r];
    __syncthreads();
    int rowb = m0 + wm + mt * 16 + quad * 4;
#pragma unroll
    for (int nt = 0; nt < 4; nt++) {
      int cc = n0 + wn + nt * 16 + l16;
      int d = cc & 127;
#pragma unroll
      for (int r = 0; r < 4; r++) {
        int row = rowb + r;
        int t = row & (S_ - 1);
        float self = acc[mt][nt][r];
        float other = Ex[pb + nt * 4 + r];
        float c = cosT[t * 128 + d], s = sinT[t * 128 + d];
        float o = (d < 64) ? (self * c - other * s) : (self * c + other * s);
        Out[(size_t)row * N + cc] = (bf16)(o * outscale);
      }
    }
  }
}

// ---------------- 256-tile pair-pipelined GEMM, optional fused RoPE -------------------
// C[M][N] = A[M][K]*B[N][K]^T. 512 thr = 8 waves (2M x 4N); per-wave C = 128x64.
// LDS 128KB: 4 A-slots (16KB = 256 rows x 64B K-half) + 4 B-slots (+65536).
// Half g (= 2t+kk) lives in slot g&3. One PAIR = one K-half = 32 MFMA, ONE barrier.
// Register pipeline: A-frags double-buffered (aE/aO); pair g issues the 8 A-reads for
// pair g+1 BEFORE its MFMA cluster (sched_barrier pins them) so the LDS pipe drains
// next-pair reads UNDER the ~1240cy MFMA cluster. B-frags (4 reads, single-buffered)
// issue right after the cluster (register WAR forbids earlier) and complete across the
// barrier. WAR-on-LDS proof: every wave does s_waitcnt lgkmcnt(0) BEFORE each barrier,
// so all reads of half g-1 (slot (g+3)&3) are complete before B(g-1), and the S(g)
// overwrite of that slot is issued after B(g-1). Provable, no timing windows.
// vmcnt ledger (4 stage-loads/pair, 3 halves in flight): before V(g) outstanding = 12;
// vmcnt(8) drains half g+1 (what R(g) reads). Tail: 8 -> 4 -> 0 -> none.
template<int FUSE_ROPE, int C_FP32>
__global__ __launch_bounds__(512, 2) void gemm256_kernel(const bf16* __restrict__ A,
                                                         const bf16* __restrict__ Bm,
                                                         void* __restrict__ Cout,
                                                         int N, int K,
                                                         const float* __restrict__ cosT,
                                                         const float* __restrict__ sinT,
                                                         float outscale) {
  __shared__ char smem[131072];
  const int tid = threadIdx.x;
  const int wave = tid >> 6, lane = tid & 63, quad = lane >> 4, l16 = lane & 15;
  const int wm = (wave >> 2) * 128, wn = (wave & 3) * 64;

  // XCD-aware bijective swizzle (grid is 16x16=256, 256%8==0)
  int bid = blockIdx.y * gridDim.x + blockIdx.x;
  int cpx = (gridDim.x * gridDim.y) >> 3;
  int wgid = (bid & 7) * cpx + (bid >> 3);
  int m0 = (wgid / gridDim.x) * 256;
  int n0 = (wgid % gridDim.x) * 256;

  // staging: LDS dest linear (slot + u*8192 + wave*1024 + lane*16) =>
  // row = u*128 + wave*16 + (lane>>2), slot16 = lane&3; pre-swizzled source chunk
  // c = (lane&3) ^ ((lane>>2)&3) ^ quad.
  const int srow = wave * 16 + (lane >> 2);
  const int sc = (lane & 3) ^ ((lane >> 2) & 3) ^ quad;
  const bf16* aS0 = A  + (size_t)(m0 + srow) * K + sc * 8;
  const bf16* aS1 = A  + (size_t)(m0 + 128 + srow) * K + sc * 8;
  const bf16* bS0 = Bm + (size_t)(n0 + srow) * K + sc * 8;
  const bf16* bS1 = Bm + (size_t)(n0 + 128 + srow) * K + sc * 8;
  const int wl = wave * 1024;

  // frag read: addr = slot + r*64 + s*16, s = quad ^ (r&3) ^ ((r>>2)&3)
  const int rslot = ((quad ^ (l16 & 3) ^ ((l16 >> 2) & 3)) << 4);
  const int aoff = (wm + l16) * 64 + rslot;
  const int boff = (wn + l16) * 64 + rslot;

  f32x4 acc[8][4];
#pragma unroll
  for (int mt = 0; mt < 8; mt++)
#pragma unroll
    for (int nt = 0; nt < 4; nt++) acc[mt][nt] = (f32x4){0.f, 0.f, 0.f, 0.f};

  bf16x8 aE[8], aO[8], b[4];

  // prologue: stage halves 0,1,2 into slots 0,1,2 (A,A,B,B per half)
#pragma unroll
  for (int h = 0; h < 3; h++) {
    char* base = smem + (h << 14);
    int koff = h * 32;
    load_lds16(aS0 + koff, base + wl);
    load_lds16(aS1 + koff, base + 8192 + wl);
    load_lds16(bS0 + koff, base + 65536 + wl);
    load_lds16(bS1 + koff, base + 65536 + 8192 + wl);
  }
  asm volatile("s_waitcnt vmcnt(8)" ::: "memory");   // half 0 landed
  __builtin_amdgcn_s_barrier();
  // preload pair-0 fragments (slot 0)
#pragma unroll
  for (int i = 0; i < 8; i++) aE[i] = *(const bf16x8*)(smem + aoff + i * 1024);
#pragma unroll
  for (int n = 0; n < 4; n++) b[n] = *(const bf16x8*)(smem + 65536 + boff + n * 1024);

  const int NT = K >> 6;
  for (int t = 0; t < NT; ++t) {
    // ======== even pair g=2t (K-half 0 of tile t): MFMA(aE,b), prefetch aO ========
    {
      if (t < NT - 1) {                      // stage half 2t+3 -> slot (2t+3)&3
        char* base = smem + (((2 * t + 3) & 3) << 14);
        int koff = (t + 1) * 64 + 32;
        load_lds16(aS0 + koff, base + wl);
        load_lds16(aS1 + koff, base + 8192 + wl);
        load_lds16(bS0 + koff, base + 65536 + wl);
        load_lds16(bS1 + koff, base + 65536 + 8192 + wl);
        asm volatile("s_waitcnt vmcnt(8)" ::: "memory");   // half 2t+1 landed
      } else {
        asm volatile("s_waitcnt vmcnt(0)" ::: "memory");
      }
      asm volatile("s_waitcnt lgkmcnt(0)" ::: "memory");   // all prior ds reads done
      __builtin_amdgcn_s_barrier();
      const char* nA = smem + (((2 * t + 1) & 3) << 14);   // k1(t)
#pragma unroll
      for (int i = 0; i < 8; i++) aO[i] = *(const bf16x8*)(nA + aoff + i * 1024);
      __builtin_amdgcn_sched_barrier(0);
      __builtin_amdgcn_s_setprio(1);
#pragma unroll
      for (int mt = 0; mt < 8; mt++)
#pragma unroll
        for (int nt = 0; nt < 4; nt++)
          acc[mt][nt] = __builtin_amdgcn_mfma_f32_16x16x32_bf16(aE[mt], b[nt], acc[mt][nt], 0, 0, 0);
      __builtin_amdgcn_s_setprio(0);
#pragma unroll
      for (int n = 0; n < 4; n++) b[n] = *(const bf16x8*)(nA + 65536 + boff + n * 1024);
    }

    // ======== odd pair g=2t+1 (K-half 1 of tile t): MFMA(aO,b), prefetch aE ========
    {
      if (t < NT - 2) {                      // stage half 2t+4 -> slot (2t)&3
        char* base = smem + (((2 * t) & 3) << 14);
        int koff = (t + 2) * 64;
        load_lds16(aS0 + koff, base + wl);
        load_lds16(aS1 + koff, base + 8192 + wl);
        load_lds16(bS0 + koff, base + 65536 + wl);
        load_lds16(bS1 + koff, base + 65536 + 8192 + wl);
        asm volatile("s_waitcnt vmcnt(8)" ::: "memory");   // half 2t+2 landed
      } else if (t == NT - 2) {
        asm volatile("s_waitcnt vmcnt(4)" ::: "memory");   // drain half 2t+2
      }
      asm volatile("s_waitcnt lgkmcnt(0)" ::: "memory");
      __builtin_amdgcn_s_barrier();
      if (t < NT - 1) {
        const char* nA = smem + (((2 * t + 2) & 3) << 14); // k0(t+1)
#pragma unroll
        for (int i = 0; i < 8; i++) aE[i] = *(const bf16x8*)(nA + aoff + i * 1024);
        __builtin_amdgcn_sched_barrier(0);
        __builtin_amdgcn_s_setprio(1);
#pragma unroll
        for (int mt = 0; mt < 8; mt++)
#pragma unroll
          for (int nt = 0; nt < 4; nt++)
            acc[mt][nt] = __builtin_amdgcn_mfma_f32_16x16x32_bf16(aO[mt], b[nt], acc[mt][nt], 0, 0, 0);
        __builtin_amdgcn_s_setprio(0);
#pragma unroll
        for (int n = 0; n < 4; n++) b[n] = *(const bf16x8*)(nA + 65536 + boff + n * 1024);
      } else {
        __builtin_amdgcn_s_setprio(1);
#pragma unroll
        for (int mt = 0; mt < 8; mt++)
#pragma unroll
          for (int nt = 0; nt < 4; nt++)
            acc[mt][nt] = __builtin_amdgcn_mfma_f32_16x16x32_bf16(aO[mt], b[nt], acc[mt][nt], 0, 0, 0);
        __builtin_amdgcn_s_setprio(0);
      }
    }
  }

  if (FUSE_ROPE) {
    float* Ex = (float*)smem;      // 512*17 floats = 34816 B, aliases tile buffers
    int myb = tid * 17;
    int pb = (tid ^ 64) * 17;      // partner owns cc^64 (wave bit0 flips), same lane/regs
#pragma unroll
    for (int mt = 0; mt < 8; mt++) {
      __syncthreads();
#pragma unroll
      for (int nt = 0; nt < 4; nt++)
#pragma unroll
        for (int r = 0; r < 4; r++)
          Ex[myb + nt * 4 + r] = acc[mt][nt][r];
      __syncthreads();
      int rowb = m0 + wm + mt * 16 + quad * 4;
#pragma unroll
      for (int nt = 0; nt < 4; nt++) {
        int cc = n0 + wn + nt * 16 + l16;
        int d = cc & 127;
#pragma unroll
        for (int r = 0; r < 4; r++) {
          int row = rowb + r;
          int tp = row & (S_ - 1);
          float self = acc[mt][nt][r];
          float other = Ex[pb + nt * 4 + r];
          float c = cosT[tp * 128 + d], s = sinT[tp * 128 + d];
          float o = (d < 64) ? (self * c - other * s) : (self * c + other * s);
          ((bf16*)Cout)[(size_t)row * N + cc] = (bf16)(o * outscale);
        }
      }
    }
  } else {
#pragma unroll
    for (int mt = 0; mt < 8; mt++)
#pragma unroll
      for (int nt = 0; nt < 4; nt++)
#pragma unroll
        for (int r = 0; r < 4; r++) {
          int rr = m0 + wm + mt * 16 + quad * 4 + r;
          int cc = n0 + wn + nt * 16 + l16;
          if (C_FP32) ((float*)Cout)[(size_t)rr * N + cc] = acc[mt][nt][r];
          else        ((bf16*)Cout)[(size_t)rr * N + cc] = (bf16)acc[mt][nt][r];
        }
  }
}

// ---------------- fused causal GQA attention -----------------------------
// grid (8, NH, B), 512 threads = 8 waves; wave owns 16 Q rows; paired q-tiles
// (qt, 15-qt) -> uniform 34 j-iterations. K double-buffered + pipelined,
// V staged behind the QK^T/softmax phase. DPP reductions, exp2-domain softmax
// (Q pre-scaled by 1/sqrt(d)*log2(e) in rope epilogue).
// v2: T13 defer-max (skip rescale unless wave max grew > 8 in log2 => P <= 256),
//     deferred denominator (per-lane psum, single red16_sum in epilogue),
//     P-store swizzle sigma(m)=2*(m>>2) (full-quad bank spread),
//     wave-uniform skip of fully-masked diagonal+64 tiles.
__global__ __launch_bounds__(512, 4) void attn_kernel(const bf16* __restrict__ Qm,
                                                      const bf16* __restrict__ Km,
                                                      const bf16* __restrict__ VtG,
                                                      bf16* __restrict__ Cm) {
  __shared__ char sK[32768];   // 2 x 16KB: addr(key,dc16)=key*256 + ((dc^(key&7))<<4)
  __shared__ char sV[16384];   // addr(d,kc8)=d*128 + ((kc^(d&7))<<4)
  __shared__ char sP[16384];   // 8 waves x 2KB: addr(m,kc8)=m*128 + ((kc ^ (2*(m>>2)))<<4)
  int tid = threadIdx.x;
  int wave = tid >> 6, lane = tid & 63, quad = lane >> 4, l16 = lane & 15;
  int h = blockIdx.y, b = blockIdx.z;
  int kvh = h >> 2;

  // staging pointers (qt-independent); each wave stages 2x1KB of K and of V
  const bf16* Kb[2];
  const bf16* Vb[2];
  {
    int r4 = lane >> 4, c16 = lane & 15;
    int r8 = lane >> 3, c8 = lane & 7;
#pragma unroll
    for (int u = 0; u < 2; u++) {
      int t = wave * 2 + u;
      int key = 4 * t + r4;
      int kc = c16 ^ (key & 7);
      Kb[u] = Km + (size_t)(b * S_ + key) * (NKV_ * HD_) + kvh * HD_ + kc * 8;
      int d = 8 * t + r8;
      int vc = c8 ^ (d & 7);
      Vb[u] = VtG + (size_t)(kvh * HD_ + d) * T_ + (size_t)b * S_ + vc * 8;
    }
  }

  for (int pass = 0; pass < 2; pass++) {
    int qt = pass ? ((S_ / 128 - 1) - (int)blockIdx.x) : (int)blockIdx.x;
    int q0 = qt * 128;
    int jend = q0 + 128;

    // pre-stage K tile j0=0 into buffer 0 (safe: pass N-1 readers are past
    // their last barrier before any wave gets here)
#pragma unroll
    for (int u = 0; u < 2; u++)
      load_lds16(Kb[u], sK + (wave * 2 + u) * 1024);

    // Q fragments: A[m=l16][k=quad*8+j]
    bf16x8 aQ[4];
    {
      int row = q0 + wave * 16 + l16;
      const bf16* qb = Qm + (size_t)(b * S_ + row) * (NH_ * HD_) + h * HD_;
#pragma unroll
      for (int kt = 0; kt < 4; kt++)
        aQ[kt] = *(const bf16x8*)(qb + kt * 32 + quad * 8);
    }

    float mcur[4], psum[4];
    f32x4 O[8];
#pragma unroll
    for (int r = 0; r < 4; r++) { mcur[r] = -1e30f; psum[r] = 0.f; }
#pragma unroll
    for (int n = 0; n < 8; n++) O[n] = (f32x4){0.f, 0.f, 0.f, 0.f};

    for (int j0 = 0; j0 < jend; j0 += 64) {
      int cur = (j0 >> 6) & 1;
      __syncthreads();   // K(cur) staged (issued one full iteration ago)
      // issue next K tile + this iteration's V tile (both land during compute)
      if (j0 + 64 < jend) {
#pragma unroll
        for (int u = 0; u < 2; u++)
          load_lds16(Kb[u] + (size_t)(j0 + 64) * (NKV_ * HD_),
                     sK + (1 - cur) * 16384 + (wave * 2 + u) * 1024);
      }
#pragma unroll
      for (int u = 0; u < 2; u++)
        load_lds16(Vb[u] + j0, sV + (wave * 2 + u) * 1024);

      // wave-uniform: is this tile entirely above the diagonal for all 16 rows?
      bool active = (j0 <= q0 + wave * 16 + 15);

      if (active) {
        // QK^T: 16 rows x 64 keys per wave
        const char* Kc = sK + cur * 16384;
        f32x4 sc[4];
#pragma unroll
        for (int nt = 0; nt < 4; nt++) sc[nt] = (f32x4){0.f, 0.f, 0.f, 0.f};
#pragma unroll
        for (int kt = 0; kt < 4; kt++) {
          bf16x8 bk[4];
#pragma unroll
          for (int nt = 0; nt < 4; nt++) {
            int key = nt * 16 + l16;
            bk[nt] = *(const bf16x8*)(Kc + key * 256 + (((kt * 4 + quad) ^ (key & 7)) << 4));
          }
#pragma unroll
          for (int nt = 0; nt < 4; nt++)
            sc[nt] = __builtin_amdgcn_mfma_f32_16x16x32_bf16(aQ[kt], bk[nt], sc[nt], 0, 0, 0);
        }

        // causal mask (wave-uniform skip for fully-visible tiles)
        int rowb = q0 + wave * 16 + quad * 4;
        if (j0 + 63 > q0 + wave * 16) {
#pragma unroll
          for (int nt = 0; nt < 4; nt++) {
            int col = j0 + nt * 16 + l16;
#pragma unroll
            for (int r = 0; r < 4; r++)
              if (col > rowb + r) sc[nt][r] = -1e9f;
          }
        }

        // defer-max online softmax: rescale only when wave max grows > 8 (log2)
        float vmax[4];
#pragma unroll
        for (int r = 0; r < 4; r++)
          vmax[r] = fmaxf(fmaxf(sc[0][r], sc[1][r]), fmaxf(sc[2][r], sc[3][r]));
        int nd = 0;
#pragma unroll
        for (int r = 0; r < 4; r++) nd |= (vmax[r] > mcur[r] + 8.f) ? 1 : 0;
        if (__any(nd)) {
          float al[4];
#pragma unroll
          for (int r = 0; r < 4; r++) {
            float rm = red16_max(vmax[r]);
            float mnew = fmaxf(mcur[r], rm);
            al[r] = exp2f(mcur[r] - mnew);
            mcur[r] = mnew;
            psum[r] *= al[r];
          }
#pragma unroll
          for (int n = 0; n < 8; n++)
#pragma unroll
            for (int r = 0; r < 4; r++) O[n][r] *= al[r];
        }
#pragma unroll
        for (int nt = 0; nt < 4; nt++)
#pragma unroll
          for (int r = 0; r < 4; r++)
            sc[nt][r] = exp2f(sc[nt][r] - mcur[r]);
#pragma unroll
        for (int r = 0; r < 4; r++)
          psum[r] += (sc[0][r] + sc[1][r]) + (sc[2][r] + sc[3][r]);

        // P -> LDS (C-layout -> A-frag layout), wave-private region
        char* Pw = sP + wave * 2048;
#pragma unroll
        for (int nt = 0; nt < 4; nt++) {
          int key = nt * 16 + l16;
#pragma unroll
          for (int r = 0; r < 4; r++) {
            int m = quad * 4 + r;
            *(bf16*)(Pw + m * 128 + ((((key >> 3) ^ (2 * quad)) & 7) << 4) + (key & 7) * 2) =
                (bf16)sc[nt][r];
          }
        }
      }

      __syncthreads();   // V(cur) staged (landed during QK^T+softmax); P visible intra-wave

      if (active) {
        // ctx += P * V
        char* Pw = sP + wave * 2048;
#pragma unroll
        for (int kt = 0; kt < 2; kt++) {
          bf16x8 ap = *(const bf16x8*)(Pw + l16 * 128 +
                      ((((kt * 4 + quad) ^ (2 * ((l16 >> 2) & 3))) & 7) << 4));
#pragma unroll
          for (int nt = 0; nt < 8; nt++) {
            int d = nt * 16 + l16;
            bf16x8 bv = *(const bf16x8*)(sV + d * 128 + (((kt * 4 + quad) ^ (d & 7)) << 4));
            O[nt] = __builtin_amdgcn_mfma_f32_16x16x32_bf16(ap, bv, O[nt], 0, 0, 0);
          }
        }
      }
    }

    // epilogue: single deferred denominator reduction, then scale
    float linv[4];
#pragma unroll
    for (int r = 0; r < 4; r++) linv[r] = 1.0f / red16_sum(psum[r]);
#pragma unroll
    for (int nt = 0; nt < 8; nt++)
#pragma unroll
      for (int r = 0; r < 4; r++) {
        int row = q0 + wave * 16 + quad * 4 + r;
        Cm[(size_t)(b * S_ + row) * (NH_ * HD_) + h * HD_ + nt * 16 + l16] =
            (bf16)(O[nt][r] * linv[r]);
      }
  }
}

extern "C" void kernel_launch(void* const* d_in, const int* in_sizes, int n_in,
                              void* d_out, int out_size, void* d_ws, size_t ws_size,
                              hipStream_t stream) {
  const float* hidden = (const float*)d_in[0];
  const float* cosT   = (const float*)d_in[1];
  const float* sinT   = (const float*)d_in[2];
  const int*   q_qw = (const int*)d_in[4];
  const float* q_sc = (const float*)d_in[5];
  const int*   k_qw = (const int*)d_in[6];
  const float* k_sc = (const float*)d_in[7];
  const int*   v_qw = (const int*)d_in[8];
  const float* v_sc = (const float*)d_in[9];
  const int*   o_qw = (const int*)d_in[10];
  const float* o_sc = (const float*)d_in[11];

  const size_t MB = 1024 * 1024;
  char* ws = (char*)d_ws;
  bf16* Xb  = (bf16*)(ws);             // 32MB  hidden bf16; later reused as ctx
  bf16* Wb  = (bf16*)(ws + 32 * MB);   // 32MB  current dequantized weight
  bf16* Qm  = (bf16*)(ws + 64 * MB);   // 32MB  [T][4096]
  bf16* Km  = (bf16*)(ws + 96 * MB);   // 8MB   [T][1024]
  bf16* VtG = (bf16*)(ws + 104 * MB);  // 8MB   [1024][T]  (V transposed)
  bf16* Cm  = Xb;

  cvt_bf16_kernel<<<(T_ * HID_ / 4 + 255) / 256, 256, 0, stream>>>(hidden, Xb, T_ * HID_ / 4);

  // Q pre-scale: 1/sqrt(128) * log2(e)  (softmax runs in exp2 domain)
  const float qscale = (float)(0.08838834764831845 * 1.4426950408889634);

  // Q projection + fused rope (256-tile pair pipeline; grid 16x16 = 256 blocks = 1/CU)
  dequant_kernel<<<(4096 * 512 + 255) / 256, 256, 0, stream>>>(q_qw, q_sc, Wb, 4096, 4096);
  gemm256_kernel<1, 0><<<dim3(16, 16), 512, 0, stream>>>(Xb, Wb, Qm, 4096, 4096,
                                                         cosT, sinT, qscale);

  // K projection + fused rope (N=1024: keep 128-tile, 256 blocks)
  dequant_kernel<<<(1024 * 512 + 255) / 256, 256, 0, stream>>>(k_qw, k_sc, Wb, 1024, 4096);
  gemm_rope_kernel<<<dim3(8, 32), 256, 0, stream>>>(Xb, Wb, Km, 1024, 4096, cosT, sinT, 1.0f);

  // V projection, written TRANSPOSED: V^T[1024][T] = Wv * X^T (keep 128-tile)
  dequant_kernel<<<(1024 * 512 + 255) / 256, 256, 0, stream>>>(v_qw, v_sc, Wb, 1024, 4096);
  gemm_bt_kernel<<<dim3(32, 8), 256, 0, stream>>>(Wb, Xb, VtG, 4096, 4096, 0);

  // attention (8 waves/block, paired q-tiles; writes Cm = Xb region)
  attn_kernel<<<dim3(8, NH_, B_), 512, 0, stream>>>(Qm, Km, VtG, Cm);

  // output projection -> fp32 d_out (256-tile pair pipeline)
  dequant_kernel<<<(4096 * 512 + 255) / 256, 256, 0, stream>>>(o_qw, o_sc, Wb, 4096, 4096);
  gemm256_kernel<0, 1><<<dim3(16, 16), 512, 0, stream>>>(Cm, Wb, d_out, 4096, 4096,
                                                         nullptr, nullptr, 1.0f);
}

// Round 5
// 785.106 us; speedup vs baseline: 2.1847x; 2.1847x over previous
//
#include <hip/hip_runtime.h>
#include <hip/hip_bf16.h>

#define B_ 2
#define S_ 2048
#define HID_ 4096
#define NH_ 32
#define NKV_ 8
#define HD_ 128
#define T_ (B_*S_)

typedef __bf16 bf16;
typedef __bf16 bf16x8 __attribute__((ext_vector_type(8)));
typedef __bf16 bf16x4 __attribute__((ext_vector_type(4)));
typedef float f32x4 __attribute__((ext_vector_type(4)));

// async global->LDS, 16B per lane; LDS dest = base + lane*16 (wave-uniform base)
__device__ __forceinline__ void load_lds16(const void* g, void* l) {
  __builtin_amdgcn_global_load_lds((const __attribute__((address_space(1))) void*)g,
                                   (__attribute__((address_space(3))) void*)l, 16, 0, 0);
}

// DPP row_ror cross-lane (16-lane ring) — VALU-speed reduction, no LDS pipe
#define DPP_ROR(x, n) __int_as_float(__builtin_amdgcn_update_dpp( \
    __float_as_int(x), __float_as_int(x), 0x120 | (n), 0xf, 0xf, false))
__device__ __forceinline__ float red16_max(float x) {
  x = fmaxf(x, DPP_ROR(x, 1)); x = fmaxf(x, DPP_ROR(x, 2));
  x = fmaxf(x, DPP_ROR(x, 4)); x = fmaxf(x, DPP_ROR(x, 8));
  return x;
}
__device__ __forceinline__ float red16_sum(float x) {
  x += DPP_ROR(x, 1); x += DPP_ROR(x, 2);
  x += DPP_ROR(x, 4); x += DPP_ROR(x, 8);
  return x;
}

// ---------------- dequant body (int4-in-int32 -> bf16), 8 elems/thread ----------------
__device__ __forceinline__ void dequant_body(const int* __restrict__ qw,
                                             const float* __restrict__ scale,
                                             bf16* __restrict__ out,
                                             int OD, int ID, int idx) {
  int perRow = ID >> 3;
  int total = OD * perRow;
  if (idx >= total) return;
  int o = idx / perRow;
  int ic = idx - o * perRow;
  float s = scale[o * (ID >> 7) + ((ic * 8) >> 7)];
  const int* q = qw + (size_t)o * ID + ic * 8;
  int4 q0 = *(const int4*)q;
  int4 q1 = *(const int4*)(q + 4);
  bf16x8 r;
  r[0] = (bf16)((q0.x - 8) * s);
  r[1] = (bf16)((q0.y - 8) * s);
  r[2] = (bf16)((q0.z - 8) * s);
  r[3] = (bf16)((q0.w - 8) * s);
  r[4] = (bf16)((q1.x - 8) * s);
  r[5] = (bf16)((q1.y - 8) * s);
  r[6] = (bf16)((q1.z - 8) * s);
  r[7] = (bf16)((q1.w - 8) * s);
  *(bf16x8*)(out + (size_t)o * ID + ic * 8) = r;
}

// ---------------- fused prep: cvt fp32->bf16  +  dequant of Q,K,V weights -----------
// block ranges: [0,16384) cvt | [16384,24576) Wq | [24576,26624) Wk | [26624,28672) Wv
__global__ __launch_bounds__(256) void prep_kernel(const float* __restrict__ hidden,
                                                   bf16* __restrict__ Xb,
                                                   const int* __restrict__ q_qw,
                                                   const float* __restrict__ q_sc,
                                                   bf16* __restrict__ Wq,
                                                   const int* __restrict__ k_qw,
                                                   const float* __restrict__ k_sc,
                                                   bf16* __restrict__ Wk,
                                                   const int* __restrict__ v_qw,
                                                   const float* __restrict__ v_sc,
                                                   bf16* __restrict__ Wv) {
  int bx = blockIdx.x;
  int tid = threadIdx.x;
  if (bx < 16384) {
    int idx = bx * 256 + tid;
    float4 v = ((const float4*)hidden)[idx];
    bf16x4 o;
    o.x = (bf16)v.x; o.y = (bf16)v.y; o.z = (bf16)v.z; o.w = (bf16)v.w;
    ((bf16x4*)Xb)[idx] = o;
  } else if (bx < 24576) {
    dequant_body(q_qw, q_sc, Wq, 4096, 4096, (bx - 16384) * 256 + tid);
  } else if (bx < 26624) {
    dequant_body(k_qw, k_sc, Wk, 1024, 4096, (bx - 24576) * 256 + tid);
  } else {
    dequant_body(v_qw, v_sc, Wv, 1024, 4096, (bx - 26624) * 256 + tid);
  }
}

// ---------------- standalone dequant (for O weight, after gemm-Q frees Wb) ----------
__global__ __launch_bounds__(256) void dequant_kernel(const int* __restrict__ qw,
                                                      const float* __restrict__ scale,
                                                      bf16* __restrict__ out,
                                                      int OD, int ID) {
  int idx = blockIdx.x * 256 + threadIdx.x;
  dequant_body(qw, scale, out, OD, ID, idx);
}

// ---------------- GEMM: C[M][N] = A[M][K] * B[N][K]^T (128-tile, kept for N=1024 shapes) ----
__global__ __launch_bounds__(256) void gemm_bt_kernel(const bf16* __restrict__ A,
                                                      const bf16* __restrict__ Bm,
                                                      void* __restrict__ Cout,
                                                      int N, int K, int c_fp32) {
  __shared__ bf16 As[8192];
  __shared__ bf16 Bs[8192];
  int tid = threadIdx.x;
  int wave = tid >> 6, lane = tid & 63, quad = lane >> 4, l16 = lane & 15;
  int m0 = blockIdx.y * 128, n0 = blockIdx.x * 128;
  int wm = (wave >> 1) * 64, wn = (wave & 1) * 64;

  int srow = lane >> 3;
  int schunk = (lane & 7) ^ (srow & 7);
  const bf16* Ab[4];
  const bf16* Bb[4];
#pragma unroll
  for (int u = 0; u < 4; u++) {
    int t = wave + 4 * u;
    Ab[u] = A  + (size_t)(m0 + 8 * t + srow) * K + schunk * 8;
    Bb[u] = Bm + (size_t)(n0 + 8 * t + srow) * K + schunk * 8;
  }

  f32x4 acc[4][4];
#pragma unroll
  for (int mt = 0; mt < 4; mt++)
#pragma unroll
    for (int nt = 0; nt < 4; nt++) acc[mt][nt] = (f32x4){0.f, 0.f, 0.f, 0.f};

  for (int k0 = 0; k0 < K; k0 += 64) {
    __syncthreads();
#pragma unroll
    for (int u = 0; u < 4; u++) {
      int t = wave + 4 * u;
      load_lds16(Ab[u] + k0, (char*)As + t * 1024);
      load_lds16(Bb[u] + k0, (char*)Bs + t * 1024);
    }
    __syncthreads();
#pragma unroll
    for (int kk = 0; kk < 2; kk++) {
      bf16x8 af[4], bfr[4];
#pragma unroll
      for (int mt = 0; mt < 4; mt++) {
        int r = wm + mt * 16 + l16;
        af[mt] = *(const bf16x8*)((const char*)As + r * 128 + (((kk * 4 + quad) ^ (r & 7)) << 4));
      }
#pragma unroll
      for (int nt = 0; nt < 4; nt++) {
        int r = wn + nt * 16 + l16;
        bfr[nt] = *(const bf16x8*)((const char*)Bs + r * 128 + (((kk * 4 + quad) ^ (r & 7)) << 4));
      }
#pragma unroll
      for (int mt = 0; mt < 4; mt++)
#pragma unroll
        for (int nt = 0; nt < 4; nt++)
          acc[mt][nt] = __builtin_amdgcn_mfma_f32_16x16x32_bf16(af[mt], bfr[nt], acc[mt][nt], 0, 0, 0);
    }
  }

#pragma unroll
  for (int mt = 0; mt < 4; mt++)
#pragma unroll
    for (int nt = 0; nt < 4; nt++)
#pragma unroll
      for (int r = 0; r < 4; r++) {
        int rr = m0 + wm + mt * 16 + quad * 4 + r;
        int cc = n0 + wn + nt * 16 + l16;
        if (c_fp32) ((float*)Cout)[(size_t)rr * N + cc] = acc[mt][nt][r];
        else        ((bf16*)Cout)[(size_t)rr * N + cc] = (bf16)acc[mt][nt][r];
      }
}

// ---------------- 128-tile GEMM + fused RoPE epilogue (kept for K projection, N=1024) ----
__global__ __launch_bounds__(256) void gemm_rope_kernel(const bf16* __restrict__ A,
                                                        const bf16* __restrict__ Bm,
                                                        bf16* __restrict__ Out,
                                                        int N, int K,
                                                        const float* __restrict__ cosT,
                                                        const float* __restrict__ sinT,
                                                        float outscale) {
  __shared__ char smem[32768];
  bf16* As = (bf16*)smem;
  bf16* Bs = (bf16*)(smem + 16384);
  float* Ex = (float*)smem;   // 256*17 floats, aliases As/Bs after main loop
  int tid = threadIdx.x;
  int wave = tid >> 6, lane = tid & 63, quad = lane >> 4, l16 = lane & 15;
  int m0 = blockIdx.y * 128, n0 = blockIdx.x * 128;
  int wm = (wave >> 1) * 64, wn = (wave & 1) * 64;

  int srow = lane >> 3;
  int schunk = (lane & 7) ^ (srow & 7);
  const bf16* Ab[4];
  const bf16* Bb[4];
#pragma unroll
  for (int u = 0; u < 4; u++) {
    int t = wave + 4 * u;
    Ab[u] = A  + (size_t)(m0 + 8 * t + srow) * K + schunk * 8;
    Bb[u] = Bm + (size_t)(n0 + 8 * t + srow) * K + schunk * 8;
  }

  f32x4 acc[4][4];
#pragma unroll
  for (int mt = 0; mt < 4; mt++)
#pragma unroll
    for (int nt = 0; nt < 4; nt++) acc[mt][nt] = (f32x4){0.f, 0.f, 0.f, 0.f};

  for (int k0 = 0; k0 < K; k0 += 64) {
    __syncthreads();
#pragma unroll
    for (int u = 0; u < 4; u++) {
      int t = wave + 4 * u;
      load_lds16(Ab[u] + k0, (char*)As + t * 1024);
      load_lds16(Bb[u] + k0, (char*)Bs + t * 1024);
    }
    __syncthreads();
#pragma unroll
    for (int kk = 0; kk < 2; kk++) {
      bf16x8 af[4], bfr[4];
#pragma unroll
      for (int mt = 0; mt < 4; mt++) {
        int r = wm + mt * 16 + l16;
        af[mt] = *(const bf16x8*)((const char*)As + r * 128 + (((kk * 4 + quad) ^ (r & 7)) << 4));
      }
#pragma unroll
      for (int nt = 0; nt < 4; nt++) {
        int r = wn + nt * 16 + l16;
        bfr[nt] = *(const bf16x8*)((const char*)Bs + r * 128 + (((kk * 4 + quad) ^ (r & 7)) << 4));
      }
#pragma unroll
      for (int mt = 0; mt < 4; mt++)
#pragma unroll
        for (int nt = 0; nt < 4; nt++)
          acc[mt][nt] = __builtin_amdgcn_mfma_f32_16x16x32_bf16(af[mt], bfr[nt], acc[mt][nt], 0, 0, 0);
    }
  }

  int myb = tid * 17;
  int pb = (tid ^ 64) * 17;    // partner: other 64-col half, same lane/regs
#pragma unroll
  for (int mt = 0; mt < 4; mt++) {
    __syncthreads();
#pragma unroll
    for (int nt = 0; nt < 4; nt++)
#pragma unroll
      for (int r = 0; r < 4; r++)
        Ex[myb + nt * 4 + r] = acc[mt][nt][r];
    __syncthreads();
    int rowb = m0 + wm + mt * 16 + quad * 4;
#pragma unroll
    for (int nt = 0; nt < 4; nt++) {
      int cc = n0 + wn + nt * 16 + l16;
      int d = cc & 127;
#pragma unroll
      for (int r = 0; r < 4; r++) {
        int row = rowb + r;
        int t = row & (S_ - 1);
        float self = acc[mt][nt][r];
        float other = Ex[pb + nt * 4 + r];
        float c = cosT[t * 128 + d], s = sinT[t * 128 + d];
        float o = (d < 64) ? (self * c - other * s) : (self * c + other * s);
        Out[(size_t)row * N + cc] = (bf16)(o * outscale);
      }
    }
  }
}

// ---------------- 256-tile 4-phase GEMM (R2-proven: 156us, 92 VGPR), optional RoPE ----
// C[M][N] = A[M][K]*B[N][K]^T. 512 thr = 8 waves (2M x 4N); per-wave C = 128x64.
// LDS 128KB: buf{0,1} x { A_k0 | A_k1 | B_k0 | B_k1 } of 16KB each ([row][64B], K-split).
// Counted waits: vmcnt(4) at phases 1 & 3 only; vmcnt(0) only prologue + last tile.
template<int FUSE_ROPE, int C_FP32>
__global__ __launch_bounds__(512, 2) void gemm256_kernel(const bf16* __restrict__ A,
                                                         const bf16* __restrict__ Bm,
                                                         void* __restrict__ Cout,
                                                         int N, int K,
                                                         const float* __restrict__ cosT,
                                                         const float* __restrict__ sinT,
                                                         float outscale) {
  __shared__ char smem[131072];
  const int tid = threadIdx.x;
  const int wave = tid >> 6, lane = tid & 63, quad = lane >> 4, l16 = lane & 15;
  const int wm = (wave >> 2) * 128, wn = (wave & 3) * 64;

  // XCD-aware bijective swizzle (grid is 16x16=256, 256%8==0)
  int bid = blockIdx.y * gridDim.x + blockIdx.x;
  int cpx = (gridDim.x * gridDim.y) >> 3;
  int wgid = (bid & 7) * cpx + (bid >> 3);
  int m0 = (wgid / gridDim.x) * 256;
  int n0 = (wgid % gridDim.x) * 256;

  const int srow = wave * 16 + (lane >> 2);
  const int sc = (lane & 3) ^ ((lane >> 2) & 3) ^ quad;
  const bf16* aS0 = A  + (size_t)(m0 + srow) * K + sc * 8;
  const bf16* aS1 = A  + (size_t)(m0 + 128 + srow) * K + sc * 8;
  const bf16* bS0 = Bm + (size_t)(n0 + srow) * K + sc * 8;
  const bf16* bS1 = Bm + (size_t)(n0 + 128 + srow) * K + sc * 8;
  const int wl = wave * 1024;

  const int rslot = ((quad ^ (l16 & 3) ^ ((l16 >> 2) & 3)) << 4);
  const int aoff = (wm + l16) * 64 + rslot;
  const int boff = (wn + l16) * 64 + rslot;

  f32x4 acc[8][4];
#pragma unroll
  for (int mt = 0; mt < 8; mt++)
#pragma unroll
    for (int nt = 0; nt < 4; nt++) acc[mt][nt] = (f32x4){0.f, 0.f, 0.f, 0.f};

  // prologue: stage all 4 halves of tile 0 into buf 0, drain once
  load_lds16(aS0,      smem +     0 + wl); load_lds16(aS1,      smem +  8192 + wl);
  load_lds16(bS0,      smem + 32768 + wl); load_lds16(bS1,      smem + 40960 + wl);
  load_lds16(aS0 + 32, smem + 16384 + wl); load_lds16(aS1 + 32, smem + 24576 + wl);
  load_lds16(bS0 + 32, smem + 49152 + wl); load_lds16(bS1 + 32, smem + 57344 + wl);
  asm volatile("s_waitcnt vmcnt(0)" ::: "memory");
  __builtin_amdgcn_s_barrier();

  const int NT = K >> 6;
  for (int t = 0; t < NT; ++t) {
    const char* base = smem + (t & 1) * 65536;
    char* nb = smem + ((t & 1) ^ 1) * 65536;
    const int off = (t + 1) << 6;      // next K-tile, in bf16 elements
    const bool more = (t + 1) < NT;
    bf16x8 afA[4], afB[4], bfr[4];

    // ---- phase 0: kk=0, rows wm..wm+63 ----
#pragma unroll
    for (int i = 0; i < 4; i++) afA[i] = *(const bf16x8*)(base + aoff + i * 1024);
#pragma unroll
    for (int i = 0; i < 4; i++) bfr[i] = *(const bf16x8*)(base + 32768 + boff + i * 1024);
    if (more) { load_lds16(aS0 + off, nb + wl); load_lds16(aS1 + off, nb + 8192 + wl); }
    __builtin_amdgcn_s_barrier();
    __builtin_amdgcn_s_setprio(1);
#pragma unroll
    for (int mt = 0; mt < 4; mt++)
#pragma unroll
      for (int nt = 0; nt < 4; nt++)
        acc[mt][nt] = __builtin_amdgcn_mfma_f32_16x16x32_bf16(afA[mt], bfr[nt], acc[mt][nt], 0, 0, 0);
    __builtin_amdgcn_s_setprio(0);
    __builtin_amdgcn_s_barrier();

    // ---- phase 1: kk=0, rows wm+64..wm+127; checkpoint: need k1 halves of tile t ----
#pragma unroll
    for (int i = 0; i < 4; i++) afB[i] = *(const bf16x8*)(base + aoff + (i + 4) * 1024);
    if (more) { load_lds16(bS0 + off, nb + 32768 + wl); load_lds16(bS1 + off, nb + 40960 + wl); }
    if (t == NT - 1) asm volatile("s_waitcnt vmcnt(0)" ::: "memory");   // epilogue drain
    else             asm volatile("s_waitcnt vmcnt(4)" ::: "memory");   // oldest 4 = k1(t)
    __builtin_amdgcn_s_barrier();
    __builtin_amdgcn_s_setprio(1);
#pragma unroll
    for (int mt = 0; mt < 4; mt++)
#pragma unroll
      for (int nt = 0; nt < 4; nt++)
        acc[mt + 4][nt] = __builtin_amdgcn_mfma_f32_16x16x32_bf16(afB[mt], bfr[nt], acc[mt + 4][nt], 0, 0, 0);
    __builtin_amdgcn_s_setprio(0);
    __builtin_amdgcn_s_barrier();

    // ---- phase 2: kk=1, rows wm..wm+63 ----
#pragma unroll
    for (int i = 0; i < 4; i++) afA[i] = *(const bf16x8*)(base + 16384 + aoff + i * 1024);
#pragma unroll
    for (int i = 0; i < 4; i++) bfr[i] = *(const bf16x8*)(base + 49152 + boff + i * 1024);
    if (more) { load_lds16(aS0 + off + 32, nb + 16384 + wl); load_lds16(aS1 + off + 32, nb + 24576 + wl); }
    __builtin_amdgcn_s_barrier();
    __builtin_amdgcn_s_setprio(1);
#pragma unroll
    for (int mt = 0; mt < 4; mt++)
#pragma unroll
      for (int nt = 0; nt < 4; nt++)
        acc[mt][nt] = __builtin_amdgcn_mfma_f32_16x16x32_bf16(afA[mt], bfr[nt], acc[mt][nt], 0, 0, 0);
    __builtin_amdgcn_s_setprio(0);
    __builtin_amdgcn_s_barrier();

    // ---- phase 3: kk=1, rows wm+64..wm+127; checkpoint: need k0 halves of tile t+1 ----
#pragma unroll
    for (int i = 0; i < 4; i++) afB[i] = *(const bf16x8*)(base + 16384 + aoff + (i + 4) * 1024);
    if (more) {
      load_lds16(bS0 + off + 32, nb + 49152 + wl); load_lds16(bS1 + off + 32, nb + 57344 + wl);
      asm volatile("s_waitcnt vmcnt(4)" ::: "memory");   // oldest 4 = k0(t+1)
    }
    __builtin_amdgcn_s_barrier();
    __builtin_amdgcn_s_setprio(1);
#pragma unroll
    for (int mt = 0; mt < 4; mt++)
#pragma unroll
      for (int nt = 0; nt < 4; nt++)
        acc[mt + 4][nt] = __builtin_amdgcn_mfma_f32_16x16x32_bf16(afB[mt], bfr[nt], acc[mt + 4][nt], 0, 0, 0);
    __builtin_amdgcn_s_setprio(0);
    __builtin_amdgcn_s_barrier();
  }

  if (FUSE_ROPE) {
    float* Ex = (float*)smem;      // 512*17 floats = 34816 B, aliases tile buffers
    int myb = tid * 17;
    int pb = (tid ^ 64) * 17;      // partner owns cc^64 (wave bit0 flips), same lane/regs
#pragma unroll
    for (int mt = 0; mt < 8; mt++) {
      __syncthreads();
#pragma unroll
      for (int nt = 0; nt < 4; nt++)
#pragma unroll
        for (int r = 0; r < 4; r++)
          Ex[myb + nt * 4 + r] = acc[mt][nt][r];
      __syncthreads();
      int rowb = m0 + wm + mt * 16 + quad * 4;
#pragma unroll
      for (int nt = 0; nt < 4; nt++) {
        int cc = n0 + wn + nt * 16 + l16;
        int d = cc & 127;
#pragma unroll
        for (int r = 0; r < 4; r++) {
          int row = rowb + r;
          int tp = row & (S_ - 1);
          float self = acc[mt][nt][r];
          float other = Ex[pb + nt * 4 + r];
          float c = cosT[tp * 128 + d], s = sinT[tp * 128 + d];
          float o = (d < 64) ? (self * c - other * s) : (self * c + other * s);
          ((bf16*)Cout)[(size_t)row * N + cc] = (bf16)(o * outscale);
        }
      }
    }
  } else {
#pragma unroll
    for (int mt = 0; mt < 8; mt++)
#pragma unroll
      for (int nt = 0; nt < 4; nt++)
#pragma unroll
        for (int r = 0; r < 4; r++) {
          int rr = m0 + wm + mt * 16 + quad * 4 + r;
          int cc = n0 + wn + nt * 16 + l16;
          if (C_FP32) ((float*)Cout)[(size_t)rr * N + cc] = acc[mt][nt][r];
          else        ((bf16*)Cout)[(size_t)rr * N + cc] = (bf16)acc[mt][nt][r];
        }
  }
}

// ---------------- fused causal GQA attention -----------------------------
// grid (8, NH, B), 512 threads = 8 waves; wave owns 16 Q rows; paired q-tiles
// (qt, 15-qt) -> uniform 34 j-iterations. K double-buffered + pipelined,
// V staged behind the QK^T/softmax phase. DPP reductions, exp2-domain softmax
// (Q pre-scaled by 1/sqrt(d)*log2(e) in rope epilogue).
// v2: T13 defer-max (skip rescale unless wave max grew > 8 in log2 => P <= 256),
//     deferred denominator (per-lane psum, single red16_sum in epilogue),
//     P-store swizzle sigma(m)=2*(m>>2) (full-quad bank spread),
//     wave-uniform skip of fully-masked diagonal+64 tiles.
__global__ __launch_bounds__(512, 4) void attn_kernel(const bf16* __restrict__ Qm,
                                                      const bf16* __restrict__ Km,
                                                      const bf16* __restrict__ VtG,
                                                      bf16* __restrict__ Cm) {
  __shared__ char sK[32768];   // 2 x 16KB: addr(key,dc16)=key*256 + ((dc^(key&7))<<4)
  __shared__ char sV[16384];   // addr(d,kc8)=d*128 + ((kc^(d&7))<<4)
  __shared__ char sP[16384];   // 8 waves x 2KB: addr(m,kc8)=m*128 + ((kc ^ (2*(m>>2)))<<4)
  int tid = threadIdx.x;
  int wave = tid >> 6, lane = tid & 63, quad = lane >> 4, l16 = lane & 15;
  int h = blockIdx.y, b = blockIdx.z;
  int kvh = h >> 2;

  // staging pointers (qt-independent); each wave stages 2x1KB of K and of V
  const bf16* Kb[2];
  const bf16* Vb[2];
  {
    int r4 = lane >> 4, c16 = lane & 15;
    int r8 = lane >> 3, c8 = lane & 7;
#pragma unroll
    for (int u = 0; u < 2; u++) {
      int t = wave * 2 + u;
      int key = 4 * t + r4;
      int kc = c16 ^ (key & 7);
      Kb[u] = Km + (size_t)(b * S_ + key) * (NKV_ * HD_) + kvh * HD_ + kc * 8;
      int d = 8 * t + r8;
      int vc = c8 ^ (d & 7);
      Vb[u] = VtG + (size_t)(kvh * HD_ + d) * T_ + (size_t)b * S_ + vc * 8;
    }
  }

  for (int pass = 0; pass < 2; pass++) {
    int qt = pass ? ((S_ / 128 - 1) - (int)blockIdx.x) : (int)blockIdx.x;
    int q0 = qt * 128;
    int jend = q0 + 128;

    // pre-stage K tile j0=0 into buffer 0 (safe: pass N-1 readers are past
    // their last barrier before any wave gets here)
#pragma unroll
    for (int u = 0; u < 2; u++)
      load_lds16(Kb[u], sK + (wave * 2 + u) * 1024);

    // Q fragments: A[m=l16][k=quad*8+j]
    bf16x8 aQ[4];
    {
      int row = q0 + wave * 16 + l16;
      const bf16* qb = Qm + (size_t)(b * S_ + row) * (NH_ * HD_) + h * HD_;
#pragma unroll
      for (int kt = 0; kt < 4; kt++)
        aQ[kt] = *(const bf16x8*)(qb + kt * 32 + quad * 8);
    }

    float mcur[4], psum[4];
    f32x4 O[8];
#pragma unroll
    for (int r = 0; r < 4; r++) { mcur[r] = -1e30f; psum[r] = 0.f; }
#pragma unroll
    for (int n = 0; n < 8; n++) O[n] = (f32x4){0.f, 0.f, 0.f, 0.f};

    for (int j0 = 0; j0 < jend; j0 += 64) {
      int cur = (j0 >> 6) & 1;
      __syncthreads();   // K(cur) staged (issued one full iteration ago)
      // issue next K tile + this iteration's V tile (both land during compute)
      if (j0 + 64 < jend) {
#pragma unroll
        for (int u = 0; u < 2; u++)
          load_lds16(Kb[u] + (size_t)(j0 + 64) * (NKV_ * HD_),
                     sK + (1 - cur) * 16384 + (wave * 2 + u) * 1024);
      }
#pragma unroll
      for (int u = 0; u < 2; u++)
        load_lds16(Vb[u] + j0, sV + (wave * 2 + u) * 1024);

      // wave-uniform: is this tile entirely above the diagonal for all 16 rows?
      bool active = (j0 <= q0 + wave * 16 + 15);

      if (active) {
        // QK^T: 16 rows x 64 keys per wave
        const char* Kc = sK + cur * 16384;
        f32x4 sc[4];
#pragma unroll
        for (int nt = 0; nt < 4; nt++) sc[nt] = (f32x4){0.f, 0.f, 0.f, 0.f};
#pragma unroll
        for (int kt = 0; kt < 4; kt++) {
          bf16x8 bk[4];
#pragma unroll
          for (int nt = 0; nt < 4; nt++) {
            int key = nt * 16 + l16;
            bk[nt] = *(const bf16x8*)(Kc + key * 256 + (((kt * 4 + quad) ^ (key & 7)) << 4));
          }
#pragma unroll
          for (int nt = 0; nt < 4; nt++)
            sc[nt] = __builtin_amdgcn_mfma_f32_16x16x32_bf16(aQ[kt], bk[nt], sc[nt], 0, 0, 0);
        }

        // causal mask (wave-uniform skip for fully-visible tiles)
        int rowb = q0 + wave * 16 + quad * 4;
        if (j0 + 63 > q0 + wave * 16) {
#pragma unroll
          for (int nt = 0; nt < 4; nt++) {
            int col = j0 + nt * 16 + l16;
#pragma unroll
            for (int r = 0; r < 4; r++)
              if (col > rowb + r) sc[nt][r] = -1e9f;
          }
        }

        // defer-max online softmax: rescale only when wave max grows > 8 (log2)
        float vmax[4];
#pragma unroll
        for (int r = 0; r < 4; r++)
          vmax[r] = fmaxf(fmaxf(sc[0][r], sc[1][r]), fmaxf(sc[2][r], sc[3][r]));
        int nd = 0;
#pragma unroll
        for (int r = 0; r < 4; r++) nd |= (vmax[r] > mcur[r] + 8.f) ? 1 : 0;
        if (__any(nd)) {
          float al[4];
#pragma unroll
          for (int r = 0; r < 4; r++) {
            float rm = red16_max(vmax[r]);
            float mnew = fmaxf(mcur[r], rm);
            al[r] = exp2f(mcur[r] - mnew);
            mcur[r] = mnew;
            psum[r] *= al[r];
          }
#pragma unroll
          for (int n = 0; n < 8; n++)
#pragma unroll
            for (int r = 0; r < 4; r++) O[n][r] *= al[r];
        }
#pragma unroll
        for (int nt = 0; nt < 4; nt++)
#pragma unroll
          for (int r = 0; r < 4; r++)
            sc[nt][r] = exp2f(sc[nt][r] - mcur[r]);
#pragma unroll
        for (int r = 0; r < 4; r++)
          psum[r] += (sc[0][r] + sc[1][r]) + (sc[2][r] + sc[3][r]);

        // P -> LDS (C-layout -> A-frag layout), wave-private region
        char* Pw = sP + wave * 2048;
#pragma unroll
        for (int nt = 0; nt < 4; nt++) {
          int key = nt * 16 + l16;
#pragma unroll
          for (int r = 0; r < 4; r++) {
            int m = quad * 4 + r;
            *(bf16*)(Pw + m * 128 + ((((key >> 3) ^ (2 * quad)) & 7) << 4) + (key & 7) * 2) =
                (bf16)sc[nt][r];
          }
        }
      }

      __syncthreads();   // V(cur) staged (landed during QK^T+softmax); P visible intra-wave

      if (active) {
        // ctx += P * V
        char* Pw = sP + wave * 2048;
#pragma unroll
        for (int kt = 0; kt < 2; kt++) {
          bf16x8 ap = *(const bf16x8*)(Pw + l16 * 128 +
                      ((((kt * 4 + quad) ^ (2 * ((l16 >> 2) & 3))) & 7) << 4));
#pragma unroll
          for (int nt = 0; nt < 8; nt++) {
            int d = nt * 16 + l16;
            bf16x8 bv = *(const bf16x8*)(sV + d * 128 + (((kt * 4 + quad) ^ (d & 7)) << 4));
            O[nt] = __builtin_amdgcn_mfma_f32_16x16x32_bf16(ap, bv, O[nt], 0, 0, 0);
          }
        }
      }
    }

    // epilogue: single deferred denominator reduction, then scale
    float linv[4];
#pragma unroll
    for (int r = 0; r < 4; r++) linv[r] = 1.0f / red16_sum(psum[r]);
#pragma unroll
    for (int nt = 0; nt < 8; nt++)
#pragma unroll
      for (int r = 0; r < 4; r++) {
        int row = q0 + wave * 16 + quad * 4 + r;
        Cm[(size_t)(b * S_ + row) * (NH_ * HD_) + h * HD_ + nt * 16 + l16] =
            (bf16)(O[nt][r] * linv[r]);
      }
  }
}

extern "C" void kernel_launch(void* const* d_in, const int* in_sizes, int n_in,
                              void* d_out, int out_size, void* d_ws, size_t ws_size,
                              hipStream_t stream) {
  const float* hidden = (const float*)d_in[0];
  const float* cosT   = (const float*)d_in[1];
  const float* sinT   = (const float*)d_in[2];
  const int*   q_qw = (const int*)d_in[4];
  const float* q_sc = (const float*)d_in[5];
  const int*   k_qw = (const int*)d_in[6];
  const float* k_sc = (const float*)d_in[7];
  const int*   v_qw = (const int*)d_in[8];
  const float* v_sc = (const float*)d_in[9];
  const int*   o_qw = (const int*)d_in[10];
  const float* o_sc = (const float*)d_in[11];

  const size_t MB = 1024 * 1024;
  char* ws = (char*)d_ws;
  bf16* Xb  = (bf16*)(ws);             // 32MB  hidden bf16; later reused as ctx
  bf16* Wb  = (bf16*)(ws + 32 * MB);   // 32MB  Wq, later Wo
  bf16* Qm  = (bf16*)(ws + 64 * MB);   // 32MB  [T][4096]; pre-gemmQ holds Wk/Wv
  bf16* Wk  = (bf16*)(ws + 64 * MB);   // 8MB   aliases Qm[0:8MB]   (consumed before gemmQ)
  bf16* Wv  = (bf16*)(ws + 72 * MB);   // 8MB   aliases Qm[8:16MB]  (consumed before gemmQ)
  bf16* Km  = (bf16*)(ws + 96 * MB);   // 8MB   [T][1024]
  bf16* VtG = (bf16*)(ws + 104 * MB);  // 8MB   [1024][T]  (V transposed)
  bf16* Cm  = Xb;

  // Q pre-scale: 1/sqrt(128) * log2(e)  (softmax runs in exp2 domain)
  const float qscale = (float)(0.08838834764831845 * 1.4426950408889634);

  // fused prep: cvt hidden->bf16 + dequant Wq/Wk/Wv (one dispatch, 28672 blocks)
  prep_kernel<<<28672, 256, 0, stream>>>(hidden, Xb, q_qw, q_sc, Wb,
                                         k_qw, k_sc, Wk, v_qw, v_sc, Wv);

  // K projection + fused rope (N=1024, 128-tile, 256 blocks) — before gemmQ (Wk in Qm region)
  gemm_rope_kernel<<<dim3(8, 32), 256, 0, stream>>>(Xb, Wk, Km, 1024, 4096, cosT, sinT, 1.0f);

  // V projection, written TRANSPOSED: V^T[1024][T] = Wv * X^T (128-tile)
  gemm_bt_kernel<<<dim3(32, 8), 256, 0, stream>>>(Wv, Xb, VtG, 4096, 4096, 0);

  // Q projection + fused rope (256-tile 4-phase; overwrites Wk/Wv region with Qm)
  gemm256_kernel<1, 0><<<dim3(16, 16), 512, 0, stream>>>(Xb, Wb, Qm, 4096, 4096,
                                                         cosT, sinT, qscale);

  // O weight dequant (Wb free after gemmQ consumed it)
  dequant_kernel<<<(4096 * 512 + 255) / 256, 256, 0, stream>>>(o_qw, o_sc, Wb, 4096, 4096);

  // attention (8 waves/block, paired q-tiles; writes Cm = Xb region)
  attn_kernel<<<dim3(8, NH_, B_), 512, 0, stream>>>(Qm, Km, VtG, Cm);

  // output projection -> fp32 d_out (256-tile 4-phase)
  gemm256_kernel<0, 1><<<dim3(16, 16), 512, 0, stream>>>(Cm, Wb, d_out, 4096, 4096,
                                                         nullptr, nullptr, 1.0f);
}